// Round 1
// baseline (839.766 us; speedup 1.0000x reference)
//
#include <hip/hip_runtime.h>
#include <hip/hip_bf16.h>
#include <hip/hip_fp16.h>

// LSTMClassifier (actually vanilla tanh RNN + FC) on MI355X.
// Pipeline: conv_w -> gemm_xproj (f16 MFMA) -> rnn_scan (persistent, batch-split)
//           -> gemm_logits (f16 MFMA, in-place over d_out).
// Precision: f16 inputs to MFMA, f32 accumulation, f32 tanh. Predicted absmax ~0.05.

typedef _Float16 half8 __attribute__((ext_vector_type(8)));
typedef float f32x4 __attribute__((ext_vector_type(4)));

#define B_DIM 512
#define T_DIM 128
#define F_DIM 512
#define H_DIM 512
#define O_DIM 256

// ---------------------------------------------------------------------------
// Weight conversion: f32 -> f16 copies of W_ih, W_hh, fc_w; bias2 = b_ih + b_hh
// ---------------------------------------------------------------------------
__global__ void conv_w(const float* __restrict__ Wih, const float* __restrict__ Whh,
                       const float* __restrict__ fcw, const float* __restrict__ bih,
                       const float* __restrict__ bhh,
                       _Float16* __restrict__ wih_h, _Float16* __restrict__ whh_h,
                       _Float16* __restrict__ fcw_h, float* __restrict__ bias2) {
    int idx = blockIdx.x * 256 + threadIdx.x;
    if (idx < 262144) {
        wih_h[idx] = (_Float16)Wih[idx];
        whh_h[idx] = (_Float16)Whh[idx];
    }
    if (idx < 131072) fcw_h[idx] = (_Float16)fcw[idx];
    if (idx < 512) bias2[idx] = bih[idx] + bhh[idx];
}

// ---------------------------------------------------------------------------
// K1: x_proj[65536,512] (f16) = states(f32)[65536,512] @ W_ih^T(f16) + bias2
// 128x128 tile, BK=32, 256 threads (4 waves, 2x2 of 64x64), reg-staged LDS.
// ---------------------------------------------------------------------------
__global__ __launch_bounds__(256) void gemm_xproj(const float* __restrict__ A,
                                                  const _Float16* __restrict__ Bw,
                                                  const float* __restrict__ bias2,
                                                  _Float16* __restrict__ out) {
    __shared__ _Float16 As[128 * 32];
    __shared__ _Float16 Bs[128 * 32];
    const int tid = threadIdx.x;
    const int m0 = (blockIdx.x >> 2) * 128;
    const int n0 = (blockIdx.x & 3) * 128;
    const int lane = tid & 63, w = tid >> 6;
    const int wr = (w >> 1) * 64, wc = (w & 1) * 64;
    const int ln = lane & 15, kg = lane >> 4;

    f32x4 acc[4][4];
#pragma unroll
    for (int m = 0; m < 4; m++)
#pragma unroll
        for (int n = 0; n < 4; n++) acc[m][n] = (f32x4)0.0f;

    const int sr = tid >> 1;            // 0..127 staging row
    const int sc = (tid & 1) * 16;      // 0 or 16

    for (int k0 = 0; k0 < 512; k0 += 32) {
        // stage A tile: f32 global -> f16 LDS
        {
            const float* ga = A + (size_t)(m0 + sr) * 512 + k0 + sc;
            float4 f0 = *(const float4*)(ga + 0);
            float4 f1 = *(const float4*)(ga + 4);
            float4 f2 = *(const float4*)(ga + 8);
            float4 f3 = *(const float4*)(ga + 12);
            half8 h0, h1;
            h0[0] = (_Float16)f0.x; h0[1] = (_Float16)f0.y; h0[2] = (_Float16)f0.z; h0[3] = (_Float16)f0.w;
            h0[4] = (_Float16)f1.x; h0[5] = (_Float16)f1.y; h0[6] = (_Float16)f1.z; h0[7] = (_Float16)f1.w;
            h1[0] = (_Float16)f2.x; h1[1] = (_Float16)f2.y; h1[2] = (_Float16)f2.z; h1[3] = (_Float16)f2.w;
            h1[4] = (_Float16)f3.x; h1[5] = (_Float16)f3.y; h1[6] = (_Float16)f3.z; h1[7] = (_Float16)f3.w;
            *(half8*)&As[sr * 32 + sc] = h0;
            *(half8*)&As[sr * 32 + sc + 8] = h1;
        }
        // stage B tile (already f16)
        {
            const _Float16* gb = Bw + (size_t)(n0 + sr) * 512 + k0 + sc;
            *(half8*)&Bs[sr * 32 + sc] = *(const half8*)(gb);
            *(half8*)&Bs[sr * 32 + sc + 8] = *(const half8*)(gb + 8);
        }
        __syncthreads();
        half8 af[4], bf[4];
#pragma unroll
        for (int m = 0; m < 4; m++) af[m] = *(const half8*)&As[(wr + m * 16 + ln) * 32 + kg * 8];
#pragma unroll
        for (int n = 0; n < 4; n++) bf[n] = *(const half8*)&Bs[(wc + n * 16 + ln) * 32 + kg * 8];
#pragma unroll
        for (int m = 0; m < 4; m++)
#pragma unroll
            for (int n = 0; n < 4; n++)
                acc[m][n] = __builtin_amdgcn_mfma_f32_16x16x32_f16(af[m], bf[n], acc[m][n], 0, 0, 0);
        __syncthreads();
    }
    // epilogue: C/D layout col=lane&15, row=(lane>>4)*4+reg
#pragma unroll
    for (int m = 0; m < 4; m++)
#pragma unroll
        for (int n = 0; n < 4; n++) {
            const int col = n0 + wc + n * 16 + ln;
            const float bv = bias2[col];
#pragma unroll
            for (int q = 0; q < 4; q++) {
                const int row = m0 + wr + m * 16 + kg * 4 + q;
                out[(size_t)row * 512 + col] = (_Float16)(acc[m][n][q] + bv);
            }
        }
}

// ---------------------------------------------------------------------------
// Scan: 32 persistent blocks x 512 threads; block owns 16 batch rows for all T.
// h in padded LDS [16][520] f16. W_hh B-fragments read directly from L2 each
// step (no LDS staging -> avoids the LDS-pipe bound). tanh in f32.
// Writes rnn_out (unmasked h_new) as f16 into the d_out logits region;
// masked carry kept in LDS; h_final (f32) written at the end.
// ---------------------------------------------------------------------------
__global__ __launch_bounds__(512) void rnn_scan(const _Float16* __restrict__ xp,
                                                const _Float16* __restrict__ Whh,
                                                const int* __restrict__ term,
                                                const float* __restrict__ h0,
                                                float* dout) {
    __shared__ _Float16 hl[16 * 520];   // padded: row stride 520 halfs (breaks bank conflicts)
    const int tid = threadIdx.x;
    const int R0 = blockIdx.x * 16;
    const int lane = tid & 63, w = tid >> 6;     // 8 waves
    const int jb = w * 64;                        // wave's 64-col slice of H
    const int ln = lane & 15, kg = lane >> 4;
    _Float16* rnn = (_Float16*)dout;              // f16 rnn_out aliased over logits region

    // init h from h0
    {
        const int r = tid >> 5, c0 = (tid & 31) * 16;
        const float* gh = h0 + (size_t)(R0 + r) * 512 + c0;
#pragma unroll
        for (int i = 0; i < 16; i++) hl[r * 520 + c0 + i] = (_Float16)gh[i];
    }
    __syncthreads();

    // W_hh row base pointers for this thread's 4 n-tiles
    const _Float16* wb0 = Whh + (size_t)(jb + 0 * 16 + ln) * 512 + kg * 8;
    const _Float16* wb1 = Whh + (size_t)(jb + 1 * 16 + ln) * 512 + kg * 8;
    const _Float16* wb2 = Whh + (size_t)(jb + 2 * 16 + ln) * 512 + kg * 8;
    const _Float16* wb3 = Whh + (size_t)(jb + 3 * 16 + ln) * 512 + kg * 8;

    for (int t = 0; t < 128; ++t) {
        f32x4 acc[4];
#pragma unroll
        for (int n = 0; n < 4; n++) acc[n] = (f32x4)0.0f;

        // prefetch x_proj values for this thread's 16 accumulator elements
        _Float16 xv[4][4];
#pragma unroll
        for (int n = 0; n < 4; n++)
#pragma unroll
            for (int q = 0; q < 4; q++) {
                const int row = kg * 4 + q;
                xv[n][q] = xp[(size_t)((R0 + row) * 128 + t) * 512 + jb + n * 16 + ln];
            }

        // K loop: 16 MFMA-K slices, double-buffered B-frags straight from L2
        half8 b0[4], b1[4];
        b0[0] = *(const half8*)(wb0); b0[1] = *(const half8*)(wb1);
        b0[2] = *(const half8*)(wb2); b0[3] = *(const half8*)(wb3);
#pragma unroll
        for (int kp = 0; kp < 8; ++kp) {
            const int k0 = kp * 64;
            b1[0] = *(const half8*)(wb0 + k0 + 32); b1[1] = *(const half8*)(wb1 + k0 + 32);
            b1[2] = *(const half8*)(wb2 + k0 + 32); b1[3] = *(const half8*)(wb3 + k0 + 32);
            half8 a0 = *(const half8*)&hl[ln * 520 + k0 + kg * 8];
#pragma unroll
            for (int n = 0; n < 4; n++) acc[n] = __builtin_amdgcn_mfma_f32_16x16x32_f16(a0, b0[n], acc[n], 0, 0, 0);
            if (kp < 7) {
                b0[0] = *(const half8*)(wb0 + k0 + 64); b0[1] = *(const half8*)(wb1 + k0 + 64);
                b0[2] = *(const half8*)(wb2 + k0 + 64); b0[3] = *(const half8*)(wb3 + k0 + 64);
            }
            half8 a1 = *(const half8*)&hl[ln * 520 + k0 + 32 + kg * 8];
#pragma unroll
            for (int n = 0; n < 4; n++) acc[n] = __builtin_amdgcn_mfma_f32_16x16x32_f16(a1, b1[n], acc[n], 0, 0, 0);
        }
        __syncthreads();   // all reads of h(t) complete

        // h_new = tanh(acc + xp) -> LDS (unmasked)
#pragma unroll
        for (int n = 0; n < 4; n++)
#pragma unroll
            for (int q = 0; q < 4; q++) {
                const float pre = acc[n][q] + (float)xv[n][q];
                const float e = __expf(2.0f * pre);
                const float hn = 1.0f - 2.0f / (e + 1.0f);   // exact identity for tanh
                hl[(kg * 4 + q) * 520 + jb + n * 16 + ln] = (_Float16)hn;
            }
        __syncthreads();   // h_new visible

        // store rnn_out (unmasked), then apply termination mask to carry in LDS
        {
            const int r = tid >> 5, c0 = (tid & 31) * 16;
            half8 v0 = *(const half8*)&hl[r * 520 + c0];
            half8 v1 = *(const half8*)&hl[r * 520 + c0 + 8];
            _Float16* gp = rnn + (size_t)((R0 + r) * 128 + t) * 512 + c0;
            *(half8*)gp = v0;
            *(half8*)(gp + 8) = v1;
            if (term[(R0 + r) * 128 + t]) {
                half8 z = {};
                *(half8*)&hl[r * 520 + c0] = z;
                *(half8*)&hl[r * 520 + c0 + 8] = z;
            }
        }
        __syncthreads();   // carry h(t+1) ready
    }

    // h_final (masked carry) -> f32 at d_out + 65536*256
    {
        const int r = tid >> 5, c0 = (tid & 31) * 16;
        float* gf = dout + (size_t)65536 * 256 + (size_t)(R0 + r) * 512 + c0;
#pragma unroll
        for (int i = 0; i < 16; i++) gf[i] = (float)hl[r * 520 + c0 + i];
    }
}

// ---------------------------------------------------------------------------
// K3: logits[65536,256] (f32) = rnn_out(f16, aliased in d_out) @ fc_w^T + fc_b
// BM=128, BN=256 (full N -> in-place per-row safe), 512 threads (2x4 waves).
// ---------------------------------------------------------------------------
__global__ __launch_bounds__(512) void gemm_logits(const _Float16* Arnn,
                                                   const _Float16* __restrict__ Bw,
                                                   const float* __restrict__ biasv,
                                                   float* out) {
    __shared__ _Float16 As[128 * 32];
    __shared__ _Float16 Bs[256 * 32];
    const int tid = threadIdx.x;
    const int m0 = blockIdx.x * 128;
    const int lane = tid & 63, w = tid >> 6;
    const int wr = (w >> 2) * 64, wc = (w & 3) * 64;
    const int ln = lane & 15, kg = lane >> 4;

    f32x4 acc[4][4];
#pragma unroll
    for (int m = 0; m < 4; m++)
#pragma unroll
        for (int n = 0; n < 4; n++) acc[m][n] = (f32x4)0.0f;

    const int ar = tid >> 2, ac = (tid & 3) * 8;    // A: 128x32, 8 halfs/thread
    const int br = tid >> 1, bc = (tid & 1) * 16;   // B: 256x32, 16 halfs/thread

    for (int k0 = 0; k0 < 512; k0 += 32) {
        *(half8*)&As[ar * 32 + ac] = *(const half8*)(Arnn + (size_t)(m0 + ar) * 512 + k0 + ac);
        {
            const _Float16* gb = Bw + (size_t)br * 512 + k0 + bc;
            *(half8*)&Bs[br * 32 + bc] = *(const half8*)(gb);
            *(half8*)&Bs[br * 32 + bc + 8] = *(const half8*)(gb + 8);
        }
        __syncthreads();
        half8 af[4], bf[4];
#pragma unroll
        for (int m = 0; m < 4; m++) af[m] = *(const half8*)&As[(wr + m * 16 + ln) * 32 + kg * 8];
#pragma unroll
        for (int n = 0; n < 4; n++) bf[n] = *(const half8*)&Bs[(wc + n * 16 + ln) * 32 + kg * 8];
#pragma unroll
        for (int m = 0; m < 4; m++)
#pragma unroll
            for (int n = 0; n < 4; n++)
                acc[m][n] = __builtin_amdgcn_mfma_f32_16x16x32_f16(af[m], bf[n], acc[m][n], 0, 0, 0);
        __syncthreads();   // also orders all A reads before the in-place epilogue stores
    }
#pragma unroll
    for (int m = 0; m < 4; m++)
#pragma unroll
        for (int n = 0; n < 4; n++) {
            const int col = wc + n * 16 + ln;
            const float bv = biasv[col];
#pragma unroll
            for (int q = 0; q < 4; q++) {
                const int row = m0 + wr + m * 16 + kg * 4 + q;
                out[(size_t)row * 256 + col] = acc[m][n][q] + bv;
            }
        }
}

// ---------------------------------------------------------------------------
extern "C" void kernel_launch(void* const* d_in, const int* in_sizes, int n_in,
                              void* d_out, int out_size, void* d_ws, size_t ws_size,
                              hipStream_t stream) {
    const float* states = (const float*)d_in[0];   // [512,128,512] f32
    const int*   term   = (const int*)d_in[1];     // [512,128] bool->int32
    const float* h0     = (const float*)d_in[2];   // [512,512] f32
    const float* Wih    = (const float*)d_in[3];   // [512,512]
    const float* Whh    = (const float*)d_in[4];   // [512,512]
    const float* bih    = (const float*)d_in[5];   // [512]
    const float* bhh    = (const float*)d_in[6];   // [512]
    const float* fcw    = (const float*)d_in[7];   // [256,512]
    const float* fcb    = (const float*)d_in[8];   // [256]

    char* ws = (char*)d_ws;
    _Float16* xpw   = (_Float16*)ws;                           // 64MB x_proj f16
    _Float16* wih_h = (_Float16*)(ws + 67108864);              // 512KB
    _Float16* whh_h = (_Float16*)(ws + 67108864 + 524288);     // 512KB
    _Float16* fcw_h = (_Float16*)(ws + 67108864 + 1048576);    // 256KB
    float*    bias2 = (float*)(ws + 67108864 + 1310720);       // 2KB

    conv_w<<<1024, 256, 0, stream>>>(Wih, Whh, fcw, bih, bhh, wih_h, whh_h, fcw_h, bias2);
    gemm_xproj<<<2048, 256, 0, stream>>>(states, wih_h, bias2, xpw);
    rnn_scan<<<32, 512, 0, stream>>>(xpw, whh_h, term, h0, (float*)d_out);
    gemm_logits<<<512, 512, 0, stream>>>((const _Float16*)d_out, fcw_h, fcb, (float*)d_out);
}

// Round 2
// 648.566 us; speedup vs baseline: 1.2948x; 1.2948x over previous
//
#include <hip/hip_runtime.h>
#include <hip/hip_bf16.h>
#include <hip/hip_fp16.h>

// tanh-RNN + FC on MI355X.
// conv_w -> gemm_xproj (f16 MFMA) -> rnn_scan2 (64 blocks: 32 batch-groups x 2
// j-halves, weights in VGPRs, pair h-exchange via agent-scope flags) ->
// gemm_logits (in-place over d_out).

typedef _Float16 half8 __attribute__((ext_vector_type(8)));
typedef float f32x4 __attribute__((ext_vector_type(4)));

// ws layout (bytes)
#define XPW_OFF   0UL            // 64MB x_proj f16
#define WIH_OFF   67108864UL     // 512KB
#define WHH_OFF   67633152UL     // 512KB
#define FCW_OFF   68157440UL     // 256KB
#define BIAS_OFF  68419584UL     // 2KB
#define HBUF_OFF  68421632UL     // 1MB: [2][512][512] f16
#define FLAGS_OFF 69470208UL     // 4KB: 64 flags, 64B apart

// swizzled h LDS byte address: row stride 1024B, XOR bits 4-6 with row&7
#define HSW(r, kb) (((r) << 10) + ((kb) ^ (((r) & 7) << 4)))

// ---------------------------------------------------------------------------
__global__ void conv_w(const float* __restrict__ Wih, const float* __restrict__ Whh,
                       const float* __restrict__ fcw, const float* __restrict__ bih,
                       const float* __restrict__ bhh,
                       _Float16* __restrict__ wih_h, _Float16* __restrict__ whh_h,
                       _Float16* __restrict__ fcw_h, float* __restrict__ bias2) {
    int idx = blockIdx.x * 256 + threadIdx.x;
    if (idx < 262144) {
        wih_h[idx] = (_Float16)Wih[idx];
        whh_h[idx] = (_Float16)Whh[idx];
    }
    if (idx < 131072) fcw_h[idx] = (_Float16)fcw[idx];
    if (idx < 512) bias2[idx] = bih[idx] + bhh[idx];
}

// ---------------------------------------------------------------------------
// K1: x_proj[65536,512] (f16) = states(f32) @ W_ih^T(f16) + bias2
// ---------------------------------------------------------------------------
__global__ __launch_bounds__(256) void gemm_xproj(const float* __restrict__ A,
                                                  const _Float16* __restrict__ Bw,
                                                  const float* __restrict__ bias2,
                                                  _Float16* __restrict__ out) {
    __shared__ _Float16 As[128 * 32];
    __shared__ _Float16 Bs[128 * 32];
    const int tid = threadIdx.x;
    const int m0 = (blockIdx.x >> 2) * 128;
    const int n0 = (blockIdx.x & 3) * 128;
    const int lane = tid & 63, w = tid >> 6;
    const int wr = (w >> 1) * 64, wc = (w & 1) * 64;
    const int ln = lane & 15, kg = lane >> 4;

    f32x4 acc[4][4];
#pragma unroll
    for (int m = 0; m < 4; m++)
#pragma unroll
        for (int n = 0; n < 4; n++) acc[m][n] = (f32x4)0.0f;

    const int sr = tid >> 1;
    const int sc = (tid & 1) * 16;

    for (int k0 = 0; k0 < 512; k0 += 32) {
        {
            const float* ga = A + (size_t)(m0 + sr) * 512 + k0 + sc;
            float4 f0 = *(const float4*)(ga + 0);
            float4 f1 = *(const float4*)(ga + 4);
            float4 f2 = *(const float4*)(ga + 8);
            float4 f3 = *(const float4*)(ga + 12);
            half8 h0, h1;
            h0[0] = (_Float16)f0.x; h0[1] = (_Float16)f0.y; h0[2] = (_Float16)f0.z; h0[3] = (_Float16)f0.w;
            h0[4] = (_Float16)f1.x; h0[5] = (_Float16)f1.y; h0[6] = (_Float16)f1.z; h0[7] = (_Float16)f1.w;
            h1[0] = (_Float16)f2.x; h1[1] = (_Float16)f2.y; h1[2] = (_Float16)f2.z; h1[3] = (_Float16)f2.w;
            h1[4] = (_Float16)f3.x; h1[5] = (_Float16)f3.y; h1[6] = (_Float16)f3.z; h1[7] = (_Float16)f3.w;
            *(half8*)&As[sr * 32 + sc] = h0;
            *(half8*)&As[sr * 32 + sc + 8] = h1;
        }
        {
            const _Float16* gb = Bw + (size_t)(n0 + sr) * 512 + k0 + sc;
            *(half8*)&Bs[sr * 32 + sc] = *(const half8*)(gb);
            *(half8*)&Bs[sr * 32 + sc + 8] = *(const half8*)(gb + 8);
        }
        __syncthreads();
        half8 af[4], bf[4];
#pragma unroll
        for (int m = 0; m < 4; m++) af[m] = *(const half8*)&As[(wr + m * 16 + ln) * 32 + kg * 8];
#pragma unroll
        for (int n = 0; n < 4; n++) bf[n] = *(const half8*)&Bs[(wc + n * 16 + ln) * 32 + kg * 8];
#pragma unroll
        for (int m = 0; m < 4; m++)
#pragma unroll
            for (int n = 0; n < 4; n++)
                acc[m][n] = __builtin_amdgcn_mfma_f32_16x16x32_f16(af[m], bf[n], acc[m][n], 0, 0, 0);
        __syncthreads();
    }
#pragma unroll
    for (int m = 0; m < 4; m++)
#pragma unroll
        for (int n = 0; n < 4; n++) {
            const int col = n0 + wc + n * 16 + ln;
            const float bv = bias2[col];
#pragma unroll
            for (int q = 0; q < 4; q++) {
                const int row = m0 + wr + m * 16 + kg * 4 + q;
                out[(size_t)row * 512 + col] = (_Float16)(acc[m][n][q] + bv);
            }
        }
}

// ---------------------------------------------------------------------------
// Scan v2: 64 blocks = 32 batch-groups x 2 j-halves. 512 thr (8 waves, 2/SIMD).
// Each wave: 2 B-tiles (32 j-cols), full-K weights in 128 VGPRs.
// h(t) own half in swizzled LDS; partner half exchanged via hbuf (agent-scope
// atomics) + monotonic flags. Own-K slices compute before the handshake.
// ---------------------------------------------------------------------------
__global__ __launch_bounds__(512, 2) void rnn_scan2(
    const _Float16* __restrict__ xp,     // [512][128][512] f16
    const _Float16* __restrict__ Whh,    // [512][512] f16
    const int* __restrict__ term,        // [512][128] int32
    const float* __restrict__ h0,        // [512][512] f32
    _Float16* __restrict__ hbuf,         // [2][512][512] f16
    int* __restrict__ flags,             // 64 flags, stride 16 ints
    float* dout) {
    __shared__ __align__(16) char hb_s[16 * 1024];     // h: 16 rows x 512 f16, swizzled
    __shared__ unsigned int term_lds[16][4];
    char* hb = hb_s;
    const int tid = threadIdx.x;
    const int bid = blockIdx.x;
    const int R0 = (bid >> 1) * 16;          // batch-row base
    const int jb0 = (bid & 1) * 256;         // own j/k half base
    const int jb0p = jb0 ^ 256;              // partner half base
    const int lane = tid & 63, w = tid >> 6;
    const int ln = lane & 15, kg = lane >> 4;
    const int jw = jb0 + w * 32;             // wave's global j base
    const int owNS = jb0 >> 5;               // own first k-slice (global, 0 or 8)
    _Float16* rnn = (_Float16*)dout;
    int* myflag = flags + bid * 16;
    int* pflag  = flags + (bid ^ 1) * 16;

    // ---- weights into VGPRs: wf[n][s_local], global slice = (owNS+s)&15 ----
    half8 wf[2][16];
#pragma unroll
    for (int n = 0; n < 2; n++) {
        const _Float16* wr_ = Whh + (size_t)(jw + n * 16 + ln) * 512 + kg * 8;
#pragma unroll
        for (int s = 0; s < 16; s++) {
            const int gs = (owNS + s) & 15;
            wf[n][s] = *(const half8*)(wr_ + gs * 32);
        }
    }

    // ---- h0 -> LDS (full 512 cols, f32->f16, swizzled) ----
    {
        const int r = tid >> 5, c0 = (tid & 31) * 16;
        const float* gh = h0 + (size_t)(R0 + r) * 512 + c0;
        half8 v0, v1;
#pragma unroll
        for (int i = 0; i < 8; i++) { v0[i] = (_Float16)gh[i]; v1[i] = (_Float16)gh[8 + i]; }
        *(half8*)(hb + HSW(r, c0 * 2)) = v0;
        *(half8*)(hb + HSW(r, c0 * 2 + 16)) = v1;
    }
    // ---- termination bitmasks ----
    if (tid < 64) {
        const int r = tid >> 2, word = tid & 3;
        unsigned int m = 0;
        for (int b = 0; b < 32; b++)
            m |= (term[(R0 + r) * 128 + word * 32 + b] ? 1u : 0u) << b;
        term_lds[r][word] = m;
    }
    __syncthreads();

    f32x4 acc[2];
    float xv[2][4];
    unsigned int tmask[4];

    // phase A for step t: xp prefetch + own-half k-slices (s_local 0..7)
    auto phaseA = [&](int t) {
#pragma unroll
        for (int n = 0; n < 2; n++)
#pragma unroll
            for (int q = 0; q < 4; q++)
                xv[n][q] = (float)xp[(size_t)((R0 + kg * 4 + q) * 128 + t) * 512 + jw + n * 16 + ln];
        acc[0] = (f32x4)0.0f; acc[1] = (f32x4)0.0f;
#pragma unroll
        for (int s = 0; s < 8; s++) {
            const int gs = (owNS + s) & 15;
            half8 a = *(const half8*)(hb + HSW(ln, gs * 64 + kg * 16));
            acc[0] = __builtin_amdgcn_mfma_f32_16x16x32_f16(a, wf[0][s], acc[0], 0, 0, 0);
            acc[1] = __builtin_amdgcn_mfma_f32_16x16x32_f16(a, wf[1][s], acc[1], 0, 0, 0);
        }
    };

    phaseA(0);
    for (int t = 0; t < 128; ++t) {
        if ((t & 31) == 0) {
#pragma unroll
            for (int q = 0; q < 4; q++) tmask[q] = term_lds[kg * 4 + q][t >> 5];
        }
        // ---- handshake: partner half of h(t) ----
        if (t > 0 && tid == 0) {
            while (__hip_atomic_load(pflag, __ATOMIC_ACQUIRE, __HIP_MEMORY_SCOPE_AGENT) < t) {}
        }
        __syncthreads();
        if (t > 0) {
            const int r = tid >> 5, ch = tid & 31;
            const unsigned long long* src = (const unsigned long long*)
                (hbuf + (size_t)(t & 1) * 262144 + (size_t)(R0 + r) * 512 + jb0p + ch * 8);
            union { half8 v; unsigned long long u[2]; } d;
            d.u[0] = __hip_atomic_load(src,     __ATOMIC_RELAXED, __HIP_MEMORY_SCOPE_AGENT);
            d.u[1] = __hip_atomic_load(src + 1, __ATOMIC_RELAXED, __HIP_MEMORY_SCOPE_AGENT);
            *(half8*)(hb + HSW(r, (jb0p + ch * 8) * 2)) = d.v;
        }
        __syncthreads();
        // ---- phase C: partner-half k-slices (s_local 8..15) ----
#pragma unroll
        for (int s = 8; s < 16; s++) {
            const int gs = (owNS + s) & 15;
            half8 a = *(const half8*)(hb + HSW(ln, gs * 64 + kg * 16));
            acc[0] = __builtin_amdgcn_mfma_f32_16x16x32_f16(a, wf[0][s], acc[0], 0, 0, 0);
            acc[1] = __builtin_amdgcn_mfma_f32_16x16x32_f16(a, wf[1][s], acc[1], 0, 0, 0);
        }
        // ---- phase D: tanh, rnn_out store (unmasked), LDS h write (masked) ----
#pragma unroll
        for (int n = 0; n < 2; n++)
#pragma unroll
            for (int q = 0; q < 4; q++) {
                const float pre = acc[n][q] + xv[n][q];
                const float e = __expf(2.0f * pre);
                const float hn = 1.0f - 2.0f / (e + 1.0f);
                rnn[(size_t)((R0 + kg * 4 + q) * 128 + t) * 512 + jw + n * 16 + ln] = (_Float16)hn;
                const _Float16 hv = ((tmask[q] >> (t & 31)) & 1) ? (_Float16)0.0f : (_Float16)hn;
                *(_Float16*)(hb + HSW(kg * 4 + q, (jw + n * 16 + ln) * 2)) = hv;
            }
        __syncthreads();   // (G) h(t+1) own half visible in LDS
        if (t < 127) {
            // ---- export own half of h(t+1) to hbuf[(t+1)&1] ----
            {
                const int r = tid >> 5, ch = tid & 31;
                union { half8 v; unsigned long long u[2]; } d;
                d.v = *(const half8*)(hb + HSW(r, (jb0 + ch * 8) * 2));
                unsigned long long* dst = (unsigned long long*)
                    (hbuf + (size_t)((t + 1) & 1) * 262144 + (size_t)(R0 + r) * 512 + jb0 + ch * 8);
                __hip_atomic_store(dst,     d.u[0], __ATOMIC_RELAXED, __HIP_MEMORY_SCOPE_AGENT);
                __hip_atomic_store(dst + 1, d.u[1], __ATOMIC_RELAXED, __HIP_MEMORY_SCOPE_AGENT);
            }
            // overlap the store drain with next step's own-half compute
            phaseA(t + 1);
            __syncthreads();   // (H) implicit vmcnt(0): exports complete
            if (tid == 0)
                __hip_atomic_store(myflag, t + 1, __ATOMIC_RELEASE, __HIP_MEMORY_SCOPE_AGENT);
        }
    }
    // ---- h_final (masked h(128), own half) ----
    {
        const int r = tid >> 5, ch = tid & 31;
        half8 v = *(const half8*)(hb + HSW(r, (jb0 + ch * 8) * 2));
        float* gf = dout + (size_t)65536 * 256 + (size_t)(R0 + r) * 512 + jb0 + ch * 8;
#pragma unroll
        for (int i = 0; i < 8; i++) gf[i] = (float)v[i];
    }
}

// ---------------------------------------------------------------------------
// K3: logits[65536,256] (f32) = rnn_out(f16, in d_out) @ fc_w^T + fc_b
// ---------------------------------------------------------------------------
__global__ __launch_bounds__(512) void gemm_logits(const _Float16* Arnn,
                                                   const _Float16* __restrict__ Bw,
                                                   const float* __restrict__ biasv,
                                                   float* out) {
    __shared__ _Float16 As[128 * 32];
    __shared__ _Float16 Bs[256 * 32];
    const int tid = threadIdx.x;
    const int m0 = blockIdx.x * 128;
    const int lane = tid & 63, w = tid >> 6;
    const int wr = (w >> 2) * 64, wc = (w & 3) * 64;
    const int ln = lane & 15, kg = lane >> 4;

    f32x4 acc[4][4];
#pragma unroll
    for (int m = 0; m < 4; m++)
#pragma unroll
        for (int n = 0; n < 4; n++) acc[m][n] = (f32x4)0.0f;

    const int ar = tid >> 2, ac = (tid & 3) * 8;
    const int br = tid >> 1, bc = (tid & 1) * 16;

    for (int k0 = 0; k0 < 512; k0 += 32) {
        *(half8*)&As[ar * 32 + ac] = *(const half8*)(Arnn + (size_t)(m0 + ar) * 512 + k0 + ac);
        {
            const _Float16* gb = Bw + (size_t)br * 512 + k0 + bc;
            *(half8*)&Bs[br * 32 + bc] = *(const half8*)(gb);
            *(half8*)&Bs[br * 32 + bc + 8] = *(const half8*)(gb + 8);
        }
        __syncthreads();
        half8 af[4], bf[4];
#pragma unroll
        for (int m = 0; m < 4; m++) af[m] = *(const half8*)&As[(wr + m * 16 + ln) * 32 + kg * 8];
#pragma unroll
        for (int n = 0; n < 4; n++) bf[n] = *(const half8*)&Bs[(wc + n * 16 + ln) * 32 + kg * 8];
#pragma unroll
        for (int m = 0; m < 4; m++)
#pragma unroll
            for (int n = 0; n < 4; n++)
                acc[m][n] = __builtin_amdgcn_mfma_f32_16x16x32_f16(af[m], bf[n], acc[m][n], 0, 0, 0);
        __syncthreads();
    }
#pragma unroll
    for (int m = 0; m < 4; m++)
#pragma unroll
        for (int n = 0; n < 4; n++) {
            const int col = wc + n * 16 + ln;
            const float bv = biasv[col];
#pragma unroll
            for (int q = 0; q < 4; q++) {
                const int row = m0 + wr + m * 16 + kg * 4 + q;
                out[(size_t)row * 256 + col] = acc[m][n][q] + bv;
            }
        }
}

// ---------------------------------------------------------------------------
extern "C" void kernel_launch(void* const* d_in, const int* in_sizes, int n_in,
                              void* d_out, int out_size, void* d_ws, size_t ws_size,
                              hipStream_t stream) {
    const float* states = (const float*)d_in[0];
    const int*   term   = (const int*)d_in[1];
    const float* h0     = (const float*)d_in[2];
    const float* Wih    = (const float*)d_in[3];
    const float* Whh    = (const float*)d_in[4];
    const float* bih    = (const float*)d_in[5];
    const float* bhh    = (const float*)d_in[6];
    const float* fcw    = (const float*)d_in[7];
    const float* fcb    = (const float*)d_in[8];

    char* ws = (char*)d_ws;
    _Float16* xpw   = (_Float16*)(ws + XPW_OFF);
    _Float16* wih_h = (_Float16*)(ws + WIH_OFF);
    _Float16* whh_h = (_Float16*)(ws + WHH_OFF);
    _Float16* fcw_h = (_Float16*)(ws + FCW_OFF);
    float*    bias2 = (float*)(ws + BIAS_OFF);
    _Float16* hbuf  = (_Float16*)(ws + HBUF_OFF);
    int*      flags = (int*)(ws + FLAGS_OFF);

    conv_w<<<1024, 256, 0, stream>>>(Wih, Whh, fcw, bih, bhh, wih_h, whh_h, fcw_h, bias2);
    gemm_xproj<<<2048, 256, 0, stream>>>(states, wih_h, bias2, xpw);
    hipMemsetAsync(flags, 0, 4096, stream);
    rnn_scan2<<<64, 512, 0, stream>>>(xpw, whh_h, term, h0, hbuf, flags, (float*)d_out);
    gemm_logits<<<512, 512, 0, stream>>>((const _Float16*)d_out, fcw_h, fcb, (float*)d_out);
}